// Round 7
// baseline (544.068 us; speedup 1.0000x reference)
//
#include <hip/hip_runtime.h>
#include <stdint.h>

#define N_TOK 4096
#define C_DIM 256
#define NSPLIT 4

typedef __attribute__((ext_vector_type(8))) short short8;
typedef __attribute__((ext_vector_type(8))) _Float16 half8;
typedef __attribute__((ext_vector_type(4))) float floatx4;
typedef __attribute__((ext_vector_type(4))) unsigned short ushort4v;

__device__ __forceinline__ unsigned short bf16_rne(float f) {
    union { float f; unsigned int u; } v; v.f = f;
    unsigned int u = v.u;
    unsigned int rounded = u + 0x7FFFu + ((u >> 16) & 1u);
    return (unsigned short)(rounded >> 16);
}
__device__ __forceinline__ float bf16_to_f(unsigned short h) {
    union { unsigned int u; float f; } v; v.u = ((unsigned int)h) << 16;
    return v.f;
}
__device__ __forceinline__ void split_bf16(float f, unsigned short& h, unsigned short& l) {
    h = bf16_rne(f);
    l = bf16_rne(f - bf16_to_f(h));
}
__device__ __forceinline__ unsigned short f2h(float f) {
    union { _Float16 h; unsigned short u; } v; v.h = (_Float16)f; return v.u;
}
__device__ __forceinline__ float h2f(unsigned short u) {
    union { unsigned short u; _Float16 h; } v; v.u = u; return (float)v.h;
}
// async global->LDS 16B/lane; LDS dest = wave-uniform base + lane*16
__device__ __forceinline__ void g2l16(const void* g, void* l) {
    __builtin_amdgcn_global_load_lds(
        (const __attribute__((address_space(1))) void*)g,
        (__attribute__((address_space(3))) void*)l, 16, 0, 0);
}
// select v[r] for r in 0..3 (cndmask chain)
__device__ __forceinline__ float sel4(const float v[4], int r) {
    float x = v[0];
    x = (r == 1) ? v[1] : x;
    x = (r == 2) ? v[2] : x;
    x = (r == 3) ? v[3] : x;
    return x;
}

// ---------------------------------------------------------------------------
// prep_kernel: one-time split/transpose (bf16 hi/lo pairs for fp32-accurate
// projection GEMM). Unchanged from R6.
// ---------------------------------------------------------------------------
__global__ __launch_bounds__(256) void prep_kernel(
    const float* __restrict__ x,
    const float* __restrict__ Wq, const float* __restrict__ Wk, const float* __restrict__ Wv,
    unsigned short* __restrict__ Xhi, unsigned short* __restrict__ Xlo,
    unsigned short* __restrict__ Whi, unsigned short* __restrict__ Wlo)
{
    const int t = threadIdx.x;
    if (blockIdx.x >= 1024) {
        const int pj = blockIdx.x - 1024;
        const float* W = (pj == 0) ? Wq : (pj == 1) ? Wk : Wv;
        unsigned short* dh = Whi + pj * 65536;
        unsigned short* dl = Wlo + pj * 65536;
        for (int it = 0; it < 64; it++) {
            const int idx = it * 1024 + t * 4;
            const float4 w = *(const float4*)&W[idx];
            unsigned short h0, l0, h1, l1, h2, l2, h3, l3;
            split_bf16(w.x, h0, l0); split_bf16(w.y, h1, l1);
            split_bf16(w.z, h2, l2); split_bf16(w.w, h3, l3);
            ushort4v vh; vh[0] = h0; vh[1] = h1; vh[2] = h2; vh[3] = h3;
            ushort4v vl; vl[0] = l0; vl[1] = l1; vl[2] = l2; vl[3] = l3;
            *(ushort4v*)&dh[idx] = vh;
            *(ushort4v*)&dl[idx] = vl;
        }
        return;
    }
    __shared__ float Xs[64 * 65];
    const int b  = blockIdx.x >> 8;
    const int ct = (blockIdx.x >> 6) & 3;
    const int nt = blockIdx.x & 63;
    const int c0 = ct * 64, n0 = nt * 64;
    {
        const int nch = t & 15, cr = t >> 4;
#pragma unroll
        for (int pass = 0; pass < 4; pass++) {
            const int c = pass * 16 + cr;
            const float4 v = *(const float4*)&x[((size_t)(b * C_DIM + c0 + c)) * N_TOK + n0 + nch * 4];
            float* row = &Xs[c * 65 + nch * 4];
            row[0] = v.x; row[1] = v.y; row[2] = v.z; row[3] = v.w;
        }
    }
    __syncthreads();
    {
        const int n = t >> 2, cc = t & 3;
        short8 vh0, vl0, vh1, vl1;
#pragma unroll
        for (int i = 0; i < 8; i++) {
            unsigned short h, l;
            split_bf16(Xs[(cc * 16 + i) * 65 + n], h, l);
            vh0[i] = (short)h; vl0[i] = (short)l;
        }
#pragma unroll
        for (int i = 0; i < 8; i++) {
            unsigned short h, l;
            split_bf16(Xs[(cc * 16 + 8 + i) * 65 + n], h, l);
            vh1[i] = (short)h; vl1[i] = (short)l;
        }
        const size_t off = ((size_t)b * N_TOK + n0 + n) * C_DIM + c0 + cc * 16;
        *(short8*)&Xhi[off] = vh0; *(short8*)&Xhi[off + 8] = vh1;
        *(short8*)&Xlo[off] = vl0; *(short8*)&Xlo[off + 8] = vl1;
    }
}

// ---------------------------------------------------------------------------
// proj_kernel: unchanged from R6 (split-bf16 3-term, fp16 outputs).
// ---------------------------------------------------------------------------
__global__ __launch_bounds__(256) void proj_kernel(
    const unsigned short* __restrict__ Xhi, const unsigned short* __restrict__ Xlo,
    const unsigned short* __restrict__ Whi, const unsigned short* __restrict__ Wlo,
    const float* __restrict__ bq, const float* __restrict__ bk, const float* __restrict__ bv,
    const float* __restrict__ relh, const float* __restrict__ relw,
    unsigned short* __restrict__ Qh,
    unsigned short* __restrict__ Kh,
    unsigned short* __restrict__ Vh)
{
    __shared__ unsigned short SM[20480];
    unsigned short* Ah = SM;
    unsigned short* Al = SM + 2048;
    unsigned short* Bh = SM + 4096;
    unsigned short* Bl = SM + 12288;

    const int t    = threadIdx.x;
    const int wave = t >> 6;
    const int lane = t & 63;
    const int l15  = lane & 15;
    const int quad = lane >> 4;

    const int bp   = blockIdx.x >> 6;
    const int proj = bp % 3;
    const int b    = bp / 3;
    const int n0   = (blockIdx.x & 63) * 64;

    const unsigned short* Xh = Xhi + ((size_t)b * N_TOK + n0) * C_DIM;
    const unsigned short* Xl = Xlo + ((size_t)b * N_TOK + n0) * C_DIM;
    const unsigned short* Wh = Whi + proj * 65536;
    const unsigned short* Wl = Wlo + proj * 65536;
    const float* bias = (proj == 0) ? bq : (proj == 1) ? bk : bv;
    const bool needlo = (proj < 2);

    floatx4 acc[16];
#pragma unroll
    for (int i = 0; i < 16; i++) acc[i] = (floatx4){0.f, 0.f, 0.f, 0.f};

    for (int c0 = 0; c0 < 256; c0 += 32) {
        {
            const int lr = lane >> 2, cp = lane & 3;
            const int key = (lr ^ (lr >> 2)) & 3;
            const int r = wave * 16 + lr;
            g2l16(Xh + (size_t)r * C_DIM + c0 + (cp ^ key) * 8, &Ah[wave * 512]);
            if (needlo) g2l16(Xl + (size_t)r * C_DIM + c0 + (cp ^ key) * 8, &Al[wave * 512]);
#pragma unroll
            for (int p = 0; p < 4; p++) {
                const int rb = (p * 4 + wave) * 16;
                const int rr = rb + lr;
                g2l16(Wh + (size_t)rr * 256 + c0 + (cp ^ key) * 8, &Bh[rb * 32]);
                if (needlo) g2l16(Wl + (size_t)rr * 256 + c0 + (cp ^ key) * 8, &Bl[rb * 32]);
            }
        }
        __syncthreads();

        const int akey = (l15 ^ (l15 >> 2)) & 3;
        const int arow = (wave * 16 + l15) * 32 + ((quad ^ akey) * 8);
        const short8 a_h = *(const short8*)&Ah[arow];
        short8 a_l;
        if (needlo) a_l = *(const short8*)&Al[arow];
#pragma unroll
        for (int ot = 0; ot < 16; ot++) {
            const int brow = (ot * 16 + l15) * 32 + ((quad ^ akey) * 8);
            const short8 b_h = *(const short8*)&Bh[brow];
            acc[ot] = __builtin_amdgcn_mfma_f32_16x16x32_bf16(a_h, b_h, acc[ot], 0, 0, 0);
            if (needlo) {
                const short8 b_l = *(const short8*)&Bl[brow];
                acc[ot] = __builtin_amdgcn_mfma_f32_16x16x32_bf16(a_l, b_h, acc[ot], 0, 0, 0);
                acc[ot] = __builtin_amdgcn_mfma_f32_16x16x32_bf16(a_h, b_l, acc[ot], 0, 0, 0);
            }
        }
        __syncthreads();
    }

    const int h0 = n0 >> 6;
    if (proj == 0) {
        unsigned short* Og = Qh + ((size_t)b * N_TOK + n0) * C_DIM;
#pragma unroll
        for (int ot = 0; ot < 16; ot++) {
            const int o = ot * 16 + l15;
            const float bs = bias[o];
#pragma unroll
            for (int r = 0; r < 4; r++) {
                const int nl = wave * 16 + quad * 4 + r;
                Og[(size_t)nl * C_DIM + o] = f2h(acc[ot][r] + bs);
            }
        }
    } else if (proj == 1) {
        unsigned short* Og = Kh + ((size_t)b * N_TOK + n0) * C_DIM;
#pragma unroll
        for (int ot = 0; ot < 16; ot++) {
            const int o = ot * 16 + l15;
            const float bs = bias[o];
            const float ph = relh[o * 64 + h0];
#pragma unroll
            for (int r = 0; r < 4; r++) {
                const int nl = wave * 16 + quad * 4 + r;
                Og[(size_t)nl * C_DIM + o] = f2h(acc[ot][r] + bs + ph + relw[o * 64 + nl]);
            }
        }
    } else {
        unsigned short* Vt = SM;
#pragma unroll
        for (int ot = 0; ot < 16; ot++) {
            const int o = ot * 16 + l15;
            const float bs = bias[o];
            const unsigned int u0 = (unsigned int)f2h(acc[ot][0] + bs) |
                                    ((unsigned int)f2h(acc[ot][1] + bs) << 16);
            const unsigned int u1 = (unsigned int)f2h(acc[ot][2] + bs) |
                                    ((unsigned int)f2h(acc[ot][3] + bs) << 16);
            uint2 uv; uv.x = u0; uv.y = u1;
            *(uint2*)&Vt[o * 72 + wave * 16 + quad * 4] = uv;
        }
        __syncthreads();
        const int ch   = t & 7;
        const int orow = t >> 3;
#pragma unroll
        for (int pass = 0; pass < 8; pass++) {
            const int o = pass * 32 + orow;
            const short8 vv = *(const short8*)&Vt[o * 72 + ch * 8];
            *(short8*)&Vh[((size_t)b * C_DIM + o) * N_TOK + n0 + ch * 8] = vv;
        }
    }
}

// ---------------------------------------------------------------------------
// flash_kernel v3: BM=128 (32 q-rows/wave), BN=64, NSPLIT=4.
// (b,s) = bid&15 (period 16 == 0 mod 8: XCD-affine, 2MB working set/XCD L2).
// K via LDS-DMA (read by all 4 waves); V loads DIRECT from L2 (no Vs buffer);
// Pt per-wave [32][64] XOR-chunk swizzled (no padding, 2-way reads).
// LDS = 48.5KB -> 2 blocks/CU; traffic-per-FLOP halved vs R6.
// ---------------------------------------------------------------------------
__global__ __launch_bounds__(256, 2) void flash_kernel(
    const unsigned short* __restrict__ Qg,   // fp16 [4][4096][256]
    const unsigned short* __restrict__ Kg,   // fp16 [4][4096][256] (k+pos)
    const unsigned short* __restrict__ Vg,   // fp16 [4][256][4096]
    unsigned short* __restrict__ Op,         // fp16 [NSPLIT][4][256][4096]
    float* __restrict__ Lm)                  // [NSPLIT][4][4096] float2 (m,l)
{
    __shared__ unsigned short Ks[64 * 256];    // 32KB  K' tile [j][c]
    __shared__ unsigned short Pt[4 * 32 * 64]; // 16KB  per-wave P^T [m][j] xor-chunk

    const int t    = threadIdx.x;
    const int wave = t >> 6;
    const int lane = t & 63;
    const int l15  = lane & 15;
    const int quad = lane >> 4;
    const int lk   = l15 & 7;

    const int bid = blockIdx.x;               // 512 = 32 qt x 4 s x 4 b
    const int b   = bid & 3;
    const int s   = (bid >> 2) & 3;
    const int qt  = bid >> 4;                 // 0..31

    const unsigned short* Kb = Kg + (size_t)b * N_TOK * C_DIM;
    const unsigned short* Vb = Vg + (size_t)b * C_DIM * N_TOK;

    // Q fragments: 32 rows x 256c per wave (2 row-groups of 16)
    half8 qf[2][8];
#pragma unroll
    for (int mg = 0; mg < 2; mg++) {
        const int qrow = qt * 128 + wave * 32 + mg * 16 + l15;
        const unsigned short* Qrow = Qg + ((size_t)b * N_TOK + qrow) * C_DIM;
#pragma unroll
        for (int ct = 0; ct < 8; ct++)
            qf[mg][ct] = *(const half8*)&Qrow[ct * 32 + quad * 8];
    }

    floatx4 oacc[2][16];
#pragma unroll
    for (int mg = 0; mg < 2; mg++)
#pragma unroll
        for (int i = 0; i < 16; i++) oacc[mg][i] = (floatx4){0.f, 0.f, 0.f, 0.f};
    float m_i[2][4] = {{-1e30f, -1e30f, -1e30f, -1e30f}, {-1e30f, -1e30f, -1e30f, -1e30f}};
    float l_i[2][4] = {{0.f, 0.f, 0.f, 0.f}, {0.f, 0.f, 0.f, 0.f}};

    unsigned short* Ptw = Pt + wave * 32 * 64;
    const int jbase = s * 1024;
    const int bsrc = ((l15 >> 2) << 4) | (l15 & 3);

    // ---- preamble: DMA K tile 0
    {
        const int lr = lane >> 5, cp = lane & 31;
#pragma unroll
        for (int p = 0; p < 8; p++) {
            const int jl = wave * 16 + p * 2 + lr;
            g2l16(Kb + (size_t)(jbase + jl) * C_DIM + (cp ^ (jl & 7)) * 8,
                  &Ks[(wave * 16 + p * 2) * 256]);
        }
    }

    for (int ti = 0; ti < 16; ti++) {
        const int j0 = jbase + ti * 64;

        __syncthreads();   // B1: K(ti) visible (vmcnt drained)

        float am[2];
#pragma unroll
        for (int mg = 0; mg < 2; mg++) {
            // ---- S = Q K'^T (single-term fp16); K fragments shared across mg
            floatx4 sv[4];
#pragma unroll
            for (int jt = 0; jt < 4; jt++) {
                floatx4 a = (floatx4){0.f, 0.f, 0.f, 0.f};
#pragma unroll
                for (int ct = 0; ct < 8; ct++) {
                    const half8 kb = *(const half8*)&Ks[(jt * 16 + l15) * 256 + (((ct * 4 + quad) ^ lk) * 8)];
                    a = __builtin_amdgcn_mfma_f32_16x16x32_f16(qf[mg][ct], kb, a, 0, 0, 0);
                }
                sv[jt] = a;
            }

            // ---- online softmax (rows mg*16 + quad*4 + r; reduce over l15)
            float alpha[4];
#pragma unroll
            for (int r = 0; r < 4; r++) {
                float mx = fmaxf(fmaxf(sv[0][r], sv[1][r]), fmaxf(sv[2][r], sv[3][r]));
                mx = fmaxf(mx, __shfl_xor(mx, 1));
                mx = fmaxf(mx, __shfl_xor(mx, 2));
                mx = fmaxf(mx, __shfl_xor(mx, 4));
                mx = fmaxf(mx, __shfl_xor(mx, 8));
                const float mn = fmaxf(m_i[mg][r], mx);
                alpha[r] = __expf(m_i[mg][r] - mn);
                m_i[mg][r] = mn;
                float ps = 0.f;
#pragma unroll
                for (int jt = 0; jt < 4; jt++) {
                    const float p = __expf(sv[jt][r] - mn);
                    sv[jt][r] = p;
                    ps += p;
                }
                ps += __shfl_xor(ps, 1);
                ps += __shfl_xor(ps, 2);
                ps += __shfl_xor(ps, 4);
                ps += __shfl_xor(ps, 8);
                l_i[mg][r] = l_i[mg][r] * alpha[r] + ps;
            }

            // ---- P^T write [m][j], chunk (j>>3) stored XOR (m&7)
#pragma unroll
            for (int jt = 0; jt < 4; jt++) {
#pragma unroll
                for (int r = 0; r < 4; r++) {
                    const int m  = mg * 16 + quad * 4 + r;
                    const int cj = jt * 2 + (l15 >> 3);
                    Ptw[m * 64 + ((cj ^ (m & 7)) << 3) + (l15 & 7)] = f2h(sv[jt][r]);
                }
            }
            am[mg] = __shfl(sel4(alpha, l15 & 3), bsrc);
        }

        __syncthreads();   // B2: all waves done reading Ks(ti)

        // ---- DMA K(ti+1) (flies under PV)
        if (ti < 15) {
            const int lr = lane >> 5, cp = lane & 31;
#pragma unroll
            for (int p = 0; p < 8; p++) {
                const int jl = wave * 16 + p * 2 + lr;
                g2l16(Kb + (size_t)(j0 + 64 + jl) * C_DIM + (cp ^ (jl & 7)) * 8,
                      &Ks[(wave * 16 + p * 2) * 256]);
            }
        }

        // ---- P^T B-fragments (per-wave Pt; lgkm-ordered, no barrier needed)
        half8 pf[2][2];
#pragma unroll
        for (int mg = 0; mg < 2; mg++) {
            const int m = mg * 16 + l15;
#pragma unroll
            for (int hf = 0; hf < 2; hf++)
                pf[mg][hf] = *(const half8*)&Ptw[m * 64 + (((hf * 4 + quad) ^ (l15 & 7)) << 3)];
        }

        // ---- rescale O by alpha
#pragma unroll
        for (int mg = 0; mg < 2; mg++)
#pragma unroll
            for (int ot = 0; ot < 16; ot++) {
                oacc[mg][ot][0] *= am[mg]; oacc[mg][ot][1] *= am[mg];
                oacc[mg][ot][2] *= am[mg]; oacc[mg][ot][3] *= am[mg];
            }

        // ---- O^T += V P^T, V A-fragments DIRECT from global (L2-resident)
#pragma unroll
        for (int ot = 0; ot < 16; ot++) {
            const unsigned short* vrow = Vb + (size_t)(ot * 16 + l15) * N_TOK + j0;
            const half8 av0 = *(const half8*)&vrow[quad * 8];
            const half8 av1 = *(const half8*)&vrow[32 + quad * 8];
            oacc[0][ot] = __builtin_amdgcn_mfma_f32_16x16x32_f16(av0, pf[0][0], oacc[0][ot], 0, 0, 0);
            oacc[0][ot] = __builtin_amdgcn_mfma_f32_16x16x32_f16(av1, pf[0][1], oacc[0][ot], 0, 0, 0);
            oacc[1][ot] = __builtin_amdgcn_mfma_f32_16x16x32_f16(av0, pf[1][0], oacc[1][ot], 0, 0, 0);
            oacc[1][ot] = __builtin_amdgcn_mfma_f32_16x16x32_f16(av1, pf[1][1], oacc[1][ot], 0, 0, 0);
        }
    }

    // ---- epilogue: unnormalized O^T fp16 + (m,l)
    unsigned short* Ob = Op + ((size_t)(s * 4 + b) * C_DIM) * N_TOK;
#pragma unroll
    for (int mg = 0; mg < 2; mg++) {
        const int n = qt * 128 + wave * 32 + mg * 16 + l15;
#pragma unroll
        for (int ot = 0; ot < 16; ot++) {
#pragma unroll
            for (int r = 0; r < 4; r++) {
                const int c = ot * 16 + quad * 4 + r;
                Ob[(size_t)c * N_TOK + n] = f2h(oacc[mg][ot][r]);
            }
        }
        if (l15 == 0) {
            const size_t nb = (size_t)(s * 4 + b) * N_TOK + qt * 128 + wave * 32 + mg * 16 + quad * 4;
#pragma unroll
            for (int r = 0; r < 4; r++)
                *(float2*)&Lm[(nb + r) * 2] = make_float2(m_i[mg][r], l_i[mg][r]);
        }
    }
}

// ---------------------------------------------------------------------------
// merge_kernel: out = gamma * (sum_s w_s O_s) / (sum_s w_s l_s) + x
// ---------------------------------------------------------------------------
__global__ __launch_bounds__(256) void merge_kernel(
    const unsigned short* __restrict__ Op,
    const float* __restrict__ Lm,
    const float* __restrict__ x,
    const float* __restrict__ gamma,
    float* __restrict__ out)
{
    const int blk = blockIdx.x;          // 4096
    const int b   = blk >> 10;
    const int c   = (blk >> 2) & 255;
    const int nq  = blk & 3;
    const int n0  = nq * 1024 + threadIdx.x * 4;

    const size_t NEo = (size_t)4 * C_DIM * N_TOK;
    const size_t obase = ((size_t)b * C_DIM + c) * N_TOK + n0;

    float ms[NSPLIT][4], ls[NSPLIT][4], os[NSPLIT][4];
#pragma unroll
    for (int s = 0; s < NSPLIT; s++) {
        const uint2 u = *(const uint2*)&Op[s * NEo + obase];
        os[s][0] = h2f((unsigned short)(u.x & 0xffff));
        os[s][1] = h2f((unsigned short)(u.x >> 16));
        os[s][2] = h2f((unsigned short)(u.y & 0xffff));
        os[s][3] = h2f((unsigned short)(u.y >> 16));
        const float* Lms = Lm + (size_t)(s * 4 + b) * N_TOK * 2;
        const float4 A0 = *(const float4*)&Lms[n0 * 2];
        const float4 A1 = *(const float4*)&Lms[n0 * 2 + 4];
        ms[s][0] = A0.x; ls[s][0] = A0.y;
        ms[s][1] = A0.z; ls[s][1] = A0.w;
        ms[s][2] = A1.x; ls[s][2] = A1.y;
        ms[s][3] = A1.z; ls[s][3] = A1.w;
    }
    const float4 xv = *(const float4*)&x[obase];
    const float xin[4] = {xv.x, xv.y, xv.z, xv.w};
    const float g = gamma[0];

    float4 res;
    float* rp = (float*)&res;
#pragma unroll
    for (int i = 0; i < 4; i++) {
        float M = ms[0][i];
#pragma unroll
        for (int s = 1; s < NSPLIT; s++) M = fmaxf(M, ms[s][i]);
        float osum = 0.f, lsum = 0.f;
#pragma unroll
        for (int s = 0; s < NSPLIT; s++) {
            const float w = __expf(ms[s][i] - M);
            osum += w * os[s][i];
            lsum += w * ls[s][i];
        }
        rp[i] = g * osum / lsum + xin[i];
    }
    *(float4*)&out[obase] = res;
}

extern "C" void kernel_launch(void* const* d_in, const int* in_sizes, int n_in,
                              void* d_out, int out_size, void* d_ws, size_t ws_size,
                              hipStream_t stream) {
    const float* x     = (const float*)d_in[0];
    const float* Wq    = (const float*)d_in[1];
    const float* bq    = (const float*)d_in[2];
    const float* Wk    = (const float*)d_in[3];
    const float* bk    = (const float*)d_in[4];
    const float* Wv    = (const float*)d_in[5];
    const float* bv    = (const float*)d_in[6];
    const float* relh  = (const float*)d_in[7];
    const float* relw  = (const float*)d_in[8];
    const float* gamma = (const float*)d_in[9];
    float* out = (float*)d_out;

    const size_t NE = (size_t)4 * N_TOK * C_DIM;   // 4.19M elems

    // Region layout (Xhi/Xlo overlay Op[0..2NE]: X dead before flash writes Op)
    unsigned short* Op  = (unsigned short*)d_ws;           // NSPLIT*NE u16
    unsigned short* Xhi = Op;                              // NE u16 (prep/proj only)
    unsigned short* Xlo = Op + NE;                         // NE u16
    unsigned short* Whi = Op + (size_t)NSPLIT * NE;        // 3*65536 u16
    unsigned short* Wlo = Whi + 3 * 65536;
    unsigned short* Qh  = Wlo + 3 * 65536;                 // NE u16 (fp16)
    unsigned short* Kh  = Qh + NE;                         // NE u16 (fp16)
    unsigned short* Vh  = Kh + NE;                         // NE u16 (fp16)
    float* Lm = (float*)(Vh + NE);                         // NSPLIT*4*4096*2 floats

    hipLaunchKernelGGL(prep_kernel, dim3(1027), dim3(256), 0, stream,
                       x, Wq, Wk, Wv, Xhi, Xlo, Whi, Wlo);
    hipLaunchKernelGGL(proj_kernel, dim3(768), dim3(256), 0, stream,
                       Xhi, Xlo, Whi, Wlo, bq, bk, bv, relh, relw, Qh, Kh, Vh);
    hipLaunchKernelGGL(flash_kernel, dim3(512), dim3(256), 0, stream,
                       Qh, Kh, Vh, Op, Lm);
    hipLaunchKernelGGL(merge_kernel, dim3(4096), dim3(256), 0, stream,
                       Op, Lm, x, gamma, out);
}

// Round 8
// 427.388 us; speedup vs baseline: 1.2730x; 1.2730x over previous
//
#include <hip/hip_runtime.h>
#include <stdint.h>

#define N_TOK 4096
#define C_DIM 256
#define NSPLIT 4

typedef __attribute__((ext_vector_type(8))) short short8;
typedef __attribute__((ext_vector_type(8))) _Float16 half8;
typedef __attribute__((ext_vector_type(4))) float floatx4;
typedef __attribute__((ext_vector_type(4))) unsigned short ushort4v;

__device__ __forceinline__ unsigned short bf16_rne(float f) {
    union { float f; unsigned int u; } v; v.f = f;
    unsigned int u = v.u;
    unsigned int rounded = u + 0x7FFFu + ((u >> 16) & 1u);
    return (unsigned short)(rounded >> 16);
}
__device__ __forceinline__ float bf16_to_f(unsigned short h) {
    union { unsigned int u; float f; } v; v.u = ((unsigned int)h) << 16;
    return v.f;
}
__device__ __forceinline__ void split_bf16(float f, unsigned short& h, unsigned short& l) {
    h = bf16_rne(f);
    l = bf16_rne(f - bf16_to_f(h));
}
__device__ __forceinline__ unsigned short f2h(float f) {
    union { _Float16 h; unsigned short u; } v; v.h = (_Float16)f; return v.u;
}
__device__ __forceinline__ float h2f(unsigned short u) {
    union { unsigned short u; _Float16 h; } v; v.u = u; return (float)v.h;
}
// async global->LDS 16B/lane; LDS dest = wave-uniform base + lane*16
__device__ __forceinline__ void g2l16(const void* g, void* l) {
    __builtin_amdgcn_global_load_lds(
        (const __attribute__((address_space(1))) void*)g,
        (__attribute__((address_space(3))) void*)l, 16, 0, 0);
}

// ---------------------------------------------------------------------------
// prep_kernel: one-time split/transpose (bf16 hi/lo pairs for fp32-accurate
// projection GEMM). Unchanged from R6.
// ---------------------------------------------------------------------------
__global__ __launch_bounds__(256) void prep_kernel(
    const float* __restrict__ x,
    const float* __restrict__ Wq, const float* __restrict__ Wk, const float* __restrict__ Wv,
    unsigned short* __restrict__ Xhi, unsigned short* __restrict__ Xlo,
    unsigned short* __restrict__ Whi, unsigned short* __restrict__ Wlo)
{
    const int t = threadIdx.x;
    if (blockIdx.x >= 1024) {
        const int pj = blockIdx.x - 1024;
        const float* W = (pj == 0) ? Wq : (pj == 1) ? Wk : Wv;
        unsigned short* dh = Whi + pj * 65536;
        unsigned short* dl = Wlo + pj * 65536;
        for (int it = 0; it < 64; it++) {
            const int idx = it * 1024 + t * 4;
            const float4 w = *(const float4*)&W[idx];
            unsigned short h0, l0, h1, l1, h2, l2, h3, l3;
            split_bf16(w.x, h0, l0); split_bf16(w.y, h1, l1);
            split_bf16(w.z, h2, l2); split_bf16(w.w, h3, l3);
            ushort4v vh; vh[0] = h0; vh[1] = h1; vh[2] = h2; vh[3] = h3;
            ushort4v vl; vl[0] = l0; vl[1] = l1; vl[2] = l2; vl[3] = l3;
            *(ushort4v*)&dh[idx] = vh;
            *(ushort4v*)&dl[idx] = vl;
        }
        return;
    }
    __shared__ float Xs[64 * 65];
    const int b  = blockIdx.x >> 8;
    const int ct = (blockIdx.x >> 6) & 3;
    const int nt = blockIdx.x & 63;
    const int c0 = ct * 64, n0 = nt * 64;
    {
        const int nch = t & 15, cr = t >> 4;
#pragma unroll
        for (int pass = 0; pass < 4; pass++) {
            const int c = pass * 16 + cr;
            const float4 v = *(const float4*)&x[((size_t)(b * C_DIM + c0 + c)) * N_TOK + n0 + nch * 4];
            float* row = &Xs[c * 65 + nch * 4];
            row[0] = v.x; row[1] = v.y; row[2] = v.z; row[3] = v.w;
        }
    }
    __syncthreads();
    {
        const int n = t >> 2, cc = t & 3;
        short8 vh0, vl0, vh1, vl1;
#pragma unroll
        for (int i = 0; i < 8; i++) {
            unsigned short h, l;
            split_bf16(Xs[(cc * 16 + i) * 65 + n], h, l);
            vh0[i] = (short)h; vl0[i] = (short)l;
        }
#pragma unroll
        for (int i = 0; i < 8; i++) {
            unsigned short h, l;
            split_bf16(Xs[(cc * 16 + 8 + i) * 65 + n], h, l);
            vh1[i] = (short)h; vl1[i] = (short)l;
        }
        const size_t off = ((size_t)b * N_TOK + n0 + n) * C_DIM + c0 + cc * 16;
        *(short8*)&Xhi[off] = vh0; *(short8*)&Xhi[off + 8] = vh1;
        *(short8*)&Xlo[off] = vl0; *(short8*)&Xlo[off + 8] = vl1;
    }
}

// ---------------------------------------------------------------------------
// proj_kernel: unchanged from R6 (split-bf16 3-term, fp16 outputs).
// ---------------------------------------------------------------------------
__global__ __launch_bounds__(256) void proj_kernel(
    const unsigned short* __restrict__ Xhi, const unsigned short* __restrict__ Xlo,
    const unsigned short* __restrict__ Whi, const unsigned short* __restrict__ Wlo,
    const float* __restrict__ bq, const float* __restrict__ bk, const float* __restrict__ bv,
    const float* __restrict__ relh, const float* __restrict__ relw,
    unsigned short* __restrict__ Qh,
    unsigned short* __restrict__ Kh,
    unsigned short* __restrict__ Vh)
{
    __shared__ unsigned short SM[20480];
    unsigned short* Ah = SM;
    unsigned short* Al = SM + 2048;
    unsigned short* Bh = SM + 4096;
    unsigned short* Bl = SM + 12288;

    const int t    = threadIdx.x;
    const int wave = t >> 6;
    const int lane = t & 63;
    const int l15  = lane & 15;
    const int quad = lane >> 4;

    const int bp   = blockIdx.x >> 6;
    const int proj = bp % 3;
    const int b    = bp / 3;
    const int n0   = (blockIdx.x & 63) * 64;

    const unsigned short* Xh = Xhi + ((size_t)b * N_TOK + n0) * C_DIM;
    const unsigned short* Xl = Xlo + ((size_t)b * N_TOK + n0) * C_DIM;
    const unsigned short* Wh = Whi + proj * 65536;
    const unsigned short* Wl = Wlo + proj * 65536;
    const float* bias = (proj == 0) ? bq : (proj == 1) ? bk : bv;
    const bool needlo = (proj < 2);

    floatx4 acc[16];
#pragma unroll
    for (int i = 0; i < 16; i++) acc[i] = (floatx4){0.f, 0.f, 0.f, 0.f};

    for (int c0 = 0; c0 < 256; c0 += 32) {
        {
            const int lr = lane >> 2, cp = lane & 3;
            const int key = (lr ^ (lr >> 2)) & 3;
            const int r = wave * 16 + lr;
            g2l16(Xh + (size_t)r * C_DIM + c0 + (cp ^ key) * 8, &Ah[wave * 512]);
            if (needlo) g2l16(Xl + (size_t)r * C_DIM + c0 + (cp ^ key) * 8, &Al[wave * 512]);
#pragma unroll
            for (int p = 0; p < 4; p++) {
                const int rb = (p * 4 + wave) * 16;
                const int rr = rb + lr;
                g2l16(Wh + (size_t)rr * 256 + c0 + (cp ^ key) * 8, &Bh[rb * 32]);
                if (needlo) g2l16(Wl + (size_t)rr * 256 + c0 + (cp ^ key) * 8, &Bl[rb * 32]);
            }
        }
        __syncthreads();

        const int akey = (l15 ^ (l15 >> 2)) & 3;
        const int arow = (wave * 16 + l15) * 32 + ((quad ^ akey) * 8);
        const short8 a_h = *(const short8*)&Ah[arow];
        short8 a_l;
        if (needlo) a_l = *(const short8*)&Al[arow];
#pragma unroll
        for (int ot = 0; ot < 16; ot++) {
            const int brow = (ot * 16 + l15) * 32 + ((quad ^ akey) * 8);
            const short8 b_h = *(const short8*)&Bh[brow];
            acc[ot] = __builtin_amdgcn_mfma_f32_16x16x32_bf16(a_h, b_h, acc[ot], 0, 0, 0);
            if (needlo) {
                const short8 b_l = *(const short8*)&Bl[brow];
                acc[ot] = __builtin_amdgcn_mfma_f32_16x16x32_bf16(a_l, b_h, acc[ot], 0, 0, 0);
                acc[ot] = __builtin_amdgcn_mfma_f32_16x16x32_bf16(a_h, b_l, acc[ot], 0, 0, 0);
            }
        }
        __syncthreads();
    }

    const int h0 = n0 >> 6;
    if (proj == 0) {
        unsigned short* Og = Qh + ((size_t)b * N_TOK + n0) * C_DIM;
#pragma unroll
        for (int ot = 0; ot < 16; ot++) {
            const int o = ot * 16 + l15;
            const float bs = bias[o];
#pragma unroll
            for (int r = 0; r < 4; r++) {
                const int nl = wave * 16 + quad * 4 + r;
                Og[(size_t)nl * C_DIM + o] = f2h(acc[ot][r] + bs);
            }
        }
    } else if (proj == 1) {
        unsigned short* Og = Kh + ((size_t)b * N_TOK + n0) * C_DIM;
#pragma unroll
        for (int ot = 0; ot < 16; ot++) {
            const int o = ot * 16 + l15;
            const float bs = bias[o];
            const float ph = relh[o * 64 + h0];
#pragma unroll
            for (int r = 0; r < 4; r++) {
                const int nl = wave * 16 + quad * 4 + r;
                Og[(size_t)nl * C_DIM + o] = f2h(acc[ot][r] + bs + ph + relw[o * 64 + nl]);
            }
        }
    } else {
        unsigned short* Vt = SM;
#pragma unroll
        for (int ot = 0; ot < 16; ot++) {
            const int o = ot * 16 + l15;
            const float bs = bias[o];
            const unsigned int u0 = (unsigned int)f2h(acc[ot][0] + bs) |
                                    ((unsigned int)f2h(acc[ot][1] + bs) << 16);
            const unsigned int u1 = (unsigned int)f2h(acc[ot][2] + bs) |
                                    ((unsigned int)f2h(acc[ot][3] + bs) << 16);
            uint2 uv; uv.x = u0; uv.y = u1;
            *(uint2*)&Vt[o * 72 + wave * 16 + quad * 4] = uv;
        }
        __syncthreads();
        const int ch   = t & 7;
        const int orow = t >> 3;
#pragma unroll
        for (int pass = 0; pass < 8; pass++) {
            const int o = pass * 32 + orow;
            const short8 vv = *(const short8*)&Vt[o * 72 + ch * 8];
            *(short8*)&Vh[((size_t)b * C_DIM + o) * N_TOK + n0 + ch * 8] = vv;
        }
    }
}

// ---------------------------------------------------------------------------
// flash_kernel v4: BM=128 (32 q-rows/wave, 2 row-groups), BN=64, NSPLIT=4.
// BOTH K and V staged via LDS-DMA (R6-proven pattern; R7's V-direct-from-L2
// thrashed L1/L2 via 8KB power-of-2 row stride -> 387MB HBM fetch).
// K-fragments and V-fragments each feed 2 MFMAs (one per row-group) ->
// LDS bytes per FLOP halved vs R6. Pt (9KB) reused sequentially per group.
// (b,s) = bid&15: period 16 == 0 mod 8 -> 2 working sets per XCD L2 (2MB).
// LDS = 75.25KB -> 2 blocks/CU.
// ---------------------------------------------------------------------------
__global__ __launch_bounds__(256, 2) void flash_kernel(
    const unsigned short* __restrict__ Qg,   // fp16 [4][4096][256]
    const unsigned short* __restrict__ Kg,   // fp16 [4][4096][256] (k+pos)
    const unsigned short* __restrict__ Vg,   // fp16 [4][256][4096]
    unsigned short* __restrict__ Op,         // fp16 [NSPLIT][4][256][4096]
    float* __restrict__ Lm)                  // [NSPLIT][4][4096] float2 (m,l)
{
    __shared__ unsigned short Ks[64 * 256];    // 32KB  K' tile [j][c]
    __shared__ unsigned short Vs[256 * 64];    // 32KB  V tile [c][j]
    __shared__ unsigned short Pt[4 * 16 * 72]; // 9KB   per-wave P^T [m][j] (per-group reuse)
    __shared__ float abuf[4][2][16];           // 512B  per-wave alpha broadcast

    const int t    = threadIdx.x;
    const int wave = t >> 6;
    const int lane = t & 63;
    const int l15  = lane & 15;
    const int quad = lane >> 4;
    const int lk   = l15 & 7;

    const int bid = blockIdx.x;               // 512 = 32 qt x 4 s x 4 b
    const int b   = bid & 3;
    const int s   = (bid >> 2) & 3;
    const int qt  = bid >> 4;                 // 0..31

    const unsigned short* Kb = Kg + (size_t)b * N_TOK * C_DIM;
    const unsigned short* Vb = Vg + (size_t)b * C_DIM * N_TOK;

    // Q fragments: 32 rows x 256c per wave (2 row-groups of 16)
    half8 qf[2][8];
#pragma unroll
    for (int mg = 0; mg < 2; mg++) {
        const int qrow = qt * 128 + wave * 32 + mg * 16 + l15;
        const unsigned short* Qrow = Qg + ((size_t)b * N_TOK + qrow) * C_DIM;
#pragma unroll
        for (int ct = 0; ct < 8; ct++)
            qf[mg][ct] = *(const half8*)&Qrow[ct * 32 + quad * 8];
    }

    floatx4 oacc[2][16];
#pragma unroll
    for (int mg = 0; mg < 2; mg++)
#pragma unroll
        for (int i = 0; i < 16; i++) oacc[mg][i] = (floatx4){0.f, 0.f, 0.f, 0.f};
    float m_i[2][4] = {{-1e30f, -1e30f, -1e30f, -1e30f}, {-1e30f, -1e30f, -1e30f, -1e30f}};
    float l_i[2][4] = {{0.f, 0.f, 0.f, 0.f}, {0.f, 0.f, 0.f, 0.f}};

    unsigned short* Ptw = Pt + wave * 16 * 72;
    const int jbase = s * 1024;

    // ---- preamble: DMA K tile 0
    {
        const int lr = lane >> 5, cp = lane & 31;
#pragma unroll
        for (int p = 0; p < 8; p++) {
            const int jl = wave * 16 + p * 2 + lr;
            g2l16(Kb + (size_t)(jbase + jl) * C_DIM + (cp ^ (jl & 7)) * 8,
                  &Ks[(wave * 16 + p * 2) * 256]);
        }
    }

    for (int ti = 0; ti < 16; ti++) {
        const int j0 = jbase + ti * 64;

        __syncthreads();   // B1: K(ti) visible (vmcnt drained); Vs(ti-1) reads done

        // ---- stage V(ti) async (flies under S-MFMAs)
        {
            const int lr = lane >> 3, cp = lane & 7;
#pragma unroll
            for (int p = 0; p < 8; p++) {
                const int ob = (p * 4 + wave) * 8;
                const int o  = ob + lr;
                g2l16(Vb + (size_t)o * N_TOK + j0 + (cp ^ (o & 7)) * 8, &Vs[ob * 64]);
            }
        }

        // ---- S = Q K'^T: each K fragment feeds both row-groups
        floatx4 sv[2][4];
#pragma unroll
        for (int jt = 0; jt < 4; jt++) {
            floatx4 a0 = (floatx4){0.f, 0.f, 0.f, 0.f};
            floatx4 a1 = (floatx4){0.f, 0.f, 0.f, 0.f};
#pragma unroll
            for (int ct = 0; ct < 8; ct++) {
                const half8 kb = *(const half8*)&Ks[(jt * 16 + l15) * 256 + (((ct * 4 + quad) ^ lk) * 8)];
                a0 = __builtin_amdgcn_mfma_f32_16x16x32_f16(qf[0][ct], kb, a0, 0, 0, 0);
                a1 = __builtin_amdgcn_mfma_f32_16x16x32_f16(qf[1][ct], kb, a1, 0, 0, 0);
            }
            sv[0][jt] = a0; sv[1][jt] = a1;
        }

        // ---- per-group: softmax, P^T to LDS, B-frags, alpha
        half8 pf[2][2];
        float am[2];
#pragma unroll
        for (int mg = 0; mg < 2; mg++) {
            float alpha[4];
#pragma unroll
            for (int r = 0; r < 4; r++) {
                float mx = fmaxf(fmaxf(sv[mg][0][r], sv[mg][1][r]), fmaxf(sv[mg][2][r], sv[mg][3][r]));
                mx = fmaxf(mx, __shfl_xor(mx, 1));
                mx = fmaxf(mx, __shfl_xor(mx, 2));
                mx = fmaxf(mx, __shfl_xor(mx, 4));
                mx = fmaxf(mx, __shfl_xor(mx, 8));
                const float mn = fmaxf(m_i[mg][r], mx);
                alpha[r] = __expf(m_i[mg][r] - mn);
                m_i[mg][r] = mn;
                float ps = 0.f;
#pragma unroll
                for (int jt = 0; jt < 4; jt++) {
                    const float p = __expf(sv[mg][jt][r] - mn);
                    sv[mg][jt][r] = p;
                    ps += p;
                }
                ps += __shfl_xor(ps, 1);
                ps += __shfl_xor(ps, 2);
                ps += __shfl_xor(ps, 4);
                ps += __shfl_xor(ps, 8);
                l_i[mg][r] = l_i[mg][r] * alpha[r] + ps;
            }
            // P^T write [m][j] pitch 72 (per-wave region; wave-local LDS ordering)
#pragma unroll
            for (int jt = 0; jt < 4; jt++) {
#pragma unroll
                for (int r = 0; r < 4; r++)
                    Ptw[(quad * 4 + r) * 72 + jt * 16 + l15] = f2h(sv[mg][jt][r]);
            }
            if (l15 == 0)
                *(float4*)&abuf[wave][mg][quad * 4] = make_float4(alpha[0], alpha[1], alpha[2], alpha[3]);
            pf[mg][0] = *(const half8*)&Ptw[l15 * 72 + quad * 8];
            pf[mg][1] = *(const half8*)&Ptw[l15 * 72 + 32 + quad * 8];
            am[mg] = abuf[wave][mg][l15];
        }

        // ---- rescale O by alpha
#pragma unroll
        for (int mg = 0; mg < 2; mg++)
#pragma unroll
            for (int ot = 0; ot < 16; ot++) {
                oacc[mg][ot][0] *= am[mg]; oacc[mg][ot][1] *= am[mg];
                oacc[mg][ot][2] *= am[mg]; oacc[mg][ot][3] *= am[mg];
            }

        __syncthreads();   // B2: V(ti) visible; all waves done reading Ks(ti)

        // ---- DMA K(ti+1) (flies under PV-MFMAs)
        if (ti < 15) {
            const int lr = lane >> 5, cp = lane & 31;
#pragma unroll
            for (int p = 0; p < 8; p++) {
                const int jl = wave * 16 + p * 2 + lr;
                g2l16(Kb + (size_t)(j0 + 64 + jl) * C_DIM + (cp ^ (jl & 7)) * 8,
                      &Ks[(wave * 16 + p * 2) * 256]);
            }
        }

        // ---- O^T += V P^T: each V fragment feeds both row-groups
#pragma unroll
        for (int ot = 0; ot < 16; ot++) {
            const int row = (ot * 16 + l15) * 64;
            const half8 av0 = *(const half8*)&Vs[row + ((quad ^ lk) * 8)];
            const half8 av1 = *(const half8*)&Vs[row + (((4 + quad) ^ lk) * 8)];
            oacc[0][ot] = __builtin_amdgcn_mfma_f32_16x16x32_f16(av0, pf[0][0], oacc[0][ot], 0, 0, 0);
            oacc[0][ot] = __builtin_amdgcn_mfma_f32_16x16x32_f16(av1, pf[0][1], oacc[0][ot], 0, 0, 0);
            oacc[1][ot] = __builtin_amdgcn_mfma_f32_16x16x32_f16(av0, pf[1][0], oacc[1][ot], 0, 0, 0);
            oacc[1][ot] = __builtin_amdgcn_mfma_f32_16x16x32_f16(av1, pf[1][1], oacc[1][ot], 0, 0, 0);
        }
    }

    // ---- epilogue: unnormalized O^T fp16 + (m,l)
    unsigned short* Ob = Op + ((size_t)(s * 4 + b) * C_DIM) * N_TOK;
#pragma unroll
    for (int mg = 0; mg < 2; mg++) {
        const int n = qt * 128 + wave * 32 + mg * 16 + l15;
#pragma unroll
        for (int ot = 0; ot < 16; ot++) {
#pragma unroll
            for (int r = 0; r < 4; r++) {
                const int c = ot * 16 + quad * 4 + r;
                Ob[(size_t)c * N_TOK + n] = f2h(oacc[mg][ot][r]);
            }
        }
        if (l15 == 0) {
            const size_t nb = (size_t)(s * 4 + b) * N_TOK + qt * 128 + wave * 32 + mg * 16 + quad * 4;
#pragma unroll
            for (int r = 0; r < 4; r++)
                *(float2*)&Lm[(nb + r) * 2] = make_float2(m_i[mg][r], l_i[mg][r]);
        }
    }
}

// ---------------------------------------------------------------------------
// merge_kernel: out = gamma * (sum_s w_s O_s) / (sum_s w_s l_s) + x
// ---------------------------------------------------------------------------
__global__ __launch_bounds__(256) void merge_kernel(
    const unsigned short* __restrict__ Op,
    const float* __restrict__ Lm,
    const float* __restrict__ x,
    const float* __restrict__ gamma,
    float* __restrict__ out)
{
    const int blk = blockIdx.x;          // 4096
    const int b   = blk >> 10;
    const int c   = (blk >> 2) & 255;
    const int nq  = blk & 3;
    const int n0  = nq * 1024 + threadIdx.x * 4;

    const size_t NEo = (size_t)4 * C_DIM * N_TOK;
    const size_t obase = ((size_t)b * C_DIM + c) * N_TOK + n0;

    float ms[NSPLIT][4], ls[NSPLIT][4], os[NSPLIT][4];
#pragma unroll
    for (int s = 0; s < NSPLIT; s++) {
        const uint2 u = *(const uint2*)&Op[s * NEo + obase];
        os[s][0] = h2f((unsigned short)(u.x & 0xffff));
        os[s][1] = h2f((unsigned short)(u.x >> 16));
        os[s][2] = h2f((unsigned short)(u.y & 0xffff));
        os[s][3] = h2f((unsigned short)(u.y >> 16));
        const float* Lms = Lm + (size_t)(s * 4 + b) * N_TOK * 2;
        const float4 A0 = *(const float4*)&Lms[n0 * 2];
        const float4 A1 = *(const float4*)&Lms[n0 * 2 + 4];
        ms[s][0] = A0.x; ls[s][0] = A0.y;
        ms[s][1] = A0.z; ls[s][1] = A0.w;
        ms[s][2] = A1.x; ls[s][2] = A1.y;
        ms[s][3] = A1.z; ls[s][3] = A1.w;
    }
    const float4 xv = *(const float4*)&x[obase];
    const float xin[4] = {xv.x, xv.y, xv.z, xv.w};
    const float g = gamma[0];

    float4 res;
    float* rp = (float*)&res;
#pragma unroll
    for (int i = 0; i < 4; i++) {
        float M = ms[0][i];
#pragma unroll
        for (int s = 1; s < NSPLIT; s++) M = fmaxf(M, ms[s][i]);
        float osum = 0.f, lsum = 0.f;
#pragma unroll
        for (int s = 0; s < NSPLIT; s++) {
            const float w = __expf(ms[s][i] - M);
            osum += w * os[s][i];
            lsum += w * ls[s][i];
        }
        rp[i] = g * osum / lsum + xin[i];
    }
    *(float4*)&out[obase] = res;
}

extern "C" void kernel_launch(void* const* d_in, const int* in_sizes, int n_in,
                              void* d_out, int out_size, void* d_ws, size_t ws_size,
                              hipStream_t stream) {
    const float* x     = (const float*)d_in[0];
    const float* Wq    = (const float*)d_in[1];
    const float* bq    = (const float*)d_in[2];
    const float* Wk    = (const float*)d_in[3];
    const float* bk    = (const float*)d_in[4];
    const float* Wv    = (const float*)d_in[5];
    const float* bv    = (const float*)d_in[6];
    const float* relh  = (const float*)d_in[7];
    const float* relw  = (const float*)d_in[8];
    const float* gamma = (const float*)d_in[9];
    float* out = (float*)d_out;

    const size_t NE = (size_t)4 * N_TOK * C_DIM;   // 4.19M elems

    // Region layout (Xhi/Xlo overlay Op[0..2NE]: X dead before flash writes Op)
    unsigned short* Op  = (unsigned short*)d_ws;           // NSPLIT*NE u16
    unsigned short* Xhi = Op;                              // NE u16 (prep/proj only)
    unsigned short* Xlo = Op + NE;                         // NE u16
    unsigned short* Whi = Op + (size_t)NSPLIT * NE;        // 3*65536 u16
    unsigned short* Wlo = Whi + 3 * 65536;
    unsigned short* Qh  = Wlo + 3 * 65536;                 // NE u16 (fp16)
    unsigned short* Kh  = Qh + NE;                         // NE u16 (fp16)
    unsigned short* Vh  = Kh + NE;                         // NE u16 (fp16)
    float* Lm = (float*)(Vh + NE);                         // NSPLIT*4*4096*2 floats

    hipLaunchKernelGGL(prep_kernel, dim3(1027), dim3(256), 0, stream,
                       x, Wq, Wk, Wv, Xhi, Xlo, Whi, Wlo);
    hipLaunchKernelGGL(proj_kernel, dim3(768), dim3(256), 0, stream,
                       Xhi, Xlo, Whi, Wlo, bq, bk, bv, relh, relw, Qh, Kh, Vh);
    hipLaunchKernelGGL(flash_kernel, dim3(512), dim3(256), 0, stream,
                       Qh, Kh, Vh, Op, Lm);
    hipLaunchKernelGGL(merge_kernel, dim3(4096), dim3(256), 0, stream,
                       Op, Lm, x, gamma, out);
}